// Round 2
// baseline (312.191 us; speedup 1.0000x reference)
//
#include <hip/hip_runtime.h>

// Problem: B=1024, F=64, D_IN=D_OUT=256, H=8, dh=32. Inputs/outputs are FLOAT32
// (reference uses jnp.float32); MFMA compute in bf16 (threshold is 2% of absmax).
typedef __attribute__((ext_vector_type(8))) short bf16x8;
typedef __attribute__((ext_vector_type(8))) unsigned short u16x8;
typedef __attribute__((ext_vector_type(4))) unsigned short u16x4;
typedef __attribute__((ext_vector_type(4))) float f32x4;
typedef unsigned short u16;

__device__ __forceinline__ float b2f(u16 u) {
    return __builtin_bit_cast(float, (unsigned)u << 16);
}
__device__ __forceinline__ u16 f2b(float f) {  // RNE f32->bf16
    unsigned i = __builtin_bit_cast(unsigned, f);
    return (u16)((i + 0x7FFFu + ((i >> 16) & 1u)) >> 16);
}

// ---- kernel 0: convert f32 weights [d][w] -> bf16 WT [w][d] (K-contig for MFMA B-op)
__global__ __launch_bounds__(256) void wtrans_kernel(
    const float* __restrict__ Q, const float* __restrict__ K, const float* __restrict__ V,
    u16* __restrict__ WT)
{
    int z = blockIdx.z; int m = z >> 6, f = z & 63;
    const float* src = (m == 0 ? Q : (m == 1 ? K : V)) + (size_t)f * 65536;
    u16* dst = WT + (size_t)z * 65536;
    int w0 = blockIdx.x * 64, d0 = blockIdx.y * 64;
    __shared__ u16 tile[64][68];
    int tid = threadIdx.x;
#pragma unroll
    for (int i = 0; i < 2; ++i) {
        int idx = tid * 2 + i; int r = idx >> 3; int c8 = (idx & 7) * 8;
        const float* p = src + (size_t)(d0 + r) * 256 + w0 + c8;
        f32x4 a = *(const f32x4*)p, b = *(const f32x4*)(p + 4);
        u16x4 lo, hi;
#pragma unroll
        for (int j = 0; j < 4; ++j) { lo[j] = f2b(a[j]); hi[j] = f2b(b[j]); }
        *(u16x4*)&tile[r][c8] = lo;
        *(u16x4*)&tile[r][c8 + 4] = hi;
    }
    __syncthreads();
#pragma unroll
    for (int i = 0; i < 2; ++i) {
        int idx = tid * 2 + i; int rw = idx >> 3; int c8 = (idx & 7) * 8;
        u16x8 v;
#pragma unroll
        for (int j = 0; j < 8; ++j) v[j] = tile[c8 + j][rw];
        *(u16x8*)(dst + (size_t)(w0 + rw) * 256 + d0 + c8) = v;
    }
}

// ---- kernel 1: q,k,v = per-f GEMM theta[:,f,:] @ W[f]; f32 A converted to bf16 in staging
__global__ __launch_bounds__(256) void qkv_gemm_kernel(
    const float* __restrict__ theta, const u16* __restrict__ WT, u16* __restrict__ ws, int B)
{
    int z = blockIdx.z; int m = z >> 6, f = z & 63;
    const float* A = theta + (size_t)f * 256;     // rows b, stride 16384 floats
    const u16* Bt = WT + (size_t)z * 65536;       // [w][d] bf16
    u16* C = ws + (size_t)m * B * 16384 + (size_t)f * 256;
    int bm0 = blockIdx.x * 128, bn0 = blockIdx.y * 128;
    __shared__ u16 As[128][32];
    __shared__ u16 Bs[128][32];
    int tid = threadIdx.x, wave = tid >> 6, lane = tid & 63;
    int l15 = lane & 15, quad = lane >> 4;
    int wm0 = (wave >> 1) * 64, wn0 = (wave & 1) * 64;
    f32x4 acc[4][4];
#pragma unroll
    for (int mi = 0; mi < 4; ++mi)
#pragma unroll
        for (int ni = 0; ni < 4; ++ni) acc[mi][ni] = f32x4{0.f, 0.f, 0.f, 0.f};
    for (int k0 = 0; k0 < 256; k0 += 32) {
#pragma unroll
        for (int i = 0; i < 2; ++i) {
            int idx = tid * 2 + i; int r = idx >> 2; int c8 = (idx & 3) * 8;
            const float* p = A + (size_t)(bm0 + r) * 16384 + k0 + c8;
            f32x4 a = *(const f32x4*)p, b = *(const f32x4*)(p + 4);
            u16x8 v;
#pragma unroll
            for (int j = 0; j < 4; ++j) { v[j] = f2b(a[j]); v[j + 4] = f2b(b[j]); }
            *(u16x8*)&As[r][c8] = v;
            *(u16x8*)&Bs[r][c8] = *(const u16x8*)(Bt + (size_t)(bn0 + r) * 256 + k0 + c8);
        }
        __syncthreads();
        bf16x8 af[4], bfr[4];
#pragma unroll
        for (int mi = 0; mi < 4; ++mi) af[mi] = *(const bf16x8*)&As[wm0 + mi * 16 + l15][quad * 8];
#pragma unroll
        for (int ni = 0; ni < 4; ++ni) bfr[ni] = *(const bf16x8*)&Bs[wn0 + ni * 16 + l15][quad * 8];
#pragma unroll
        for (int mi = 0; mi < 4; ++mi)
#pragma unroll
            for (int ni = 0; ni < 4; ++ni)
                acc[mi][ni] = __builtin_amdgcn_mfma_f32_16x16x32_bf16(af[mi], bfr[ni], acc[mi][ni], 0, 0, 0);
        __syncthreads();
    }
#pragma unroll
    for (int mi = 0; mi < 4; ++mi)
#pragma unroll
        for (int ni = 0; ni < 4; ++ni)
#pragma unroll
            for (int r = 0; r < 4; ++r)
                C[(size_t)(bm0 + wm0 + mi * 16 + quad * 4 + r) * 16384 + bn0 + wn0 + ni * 16 + l15] =
                    f2b(acc[mi][ni][r]);
}

// ---- kernel 2: attention. 1 block per b, 1 wave per head (x2 sequential heads).
// logits = [cos(q)*rw | sin(q)*rw] @ [cos(k) | sin(k)]^T (K=64), S=sigmoid, out=S@V (f32 -> d_out).
__global__ __launch_bounds__(256) void attn_kernel(
    const u16* __restrict__ qws, const u16* __restrict__ kws, const u16* __restrict__ vws,
    float* __restrict__ attf, const float* __restrict__ rotw)
{
    int b = blockIdx.x;
    int tid = threadIdx.x, wave = tid >> 6, lane = tid & 63;
    int l15 = lane & 15, quad = lane >> 4;
    __shared__ u16 Sb[4][64][72];   // wave-private slices; padded for conflict-free b128 reads
    __shared__ u16 Vb[4][64][32];
    const size_t base = (size_t)b * (64 * 256);
    float rw[8];
    {
        f32x4 r0 = *(const f32x4*)(rotw + quad * 8);
        f32x4 r1 = *(const f32x4*)(rotw + quad * 8 + 4);
#pragma unroll
        for (int j = 0; j < 4; ++j) { rw[j] = r0[j]; rw[j + 4] = r1[j]; }
    }
    for (int hi = 0; hi < 2; ++hi) {
        int h = wave + hi * 4;
        const u16* qh = qws + base + h * 32;
        const u16* kh = kws + base + h * 32;
        const u16* vh = vws + base + h * 32;
#pragma unroll
        for (int i = 0; i < 4; ++i) {
            int row = i * 16 + (lane >> 2); int c8 = (lane & 3) * 8;
            *(u16x8*)&Vb[wave][row][c8] = *(const u16x8*)(vh + (size_t)row * 256 + c8);
        }
        bf16x8 af[4][2], bfr[4][2];
#pragma unroll
        for (int mi = 0; mi < 4; ++mi) {
            u16x8 q8 = *(const u16x8*)(qh + (size_t)(mi * 16 + l15) * 256 + quad * 8);
            bf16x8 c, s;
#pragma unroll
            for (int j = 0; j < 8; ++j) {
                float v = b2f(q8[j]);
                c[j] = (short)f2b(__cosf(v) * rw[j]);
                s[j] = (short)f2b(__sinf(v) * rw[j]);
            }
            af[mi][0] = c; af[mi][1] = s;
        }
#pragma unroll
        for (int ni = 0; ni < 4; ++ni) {
            u16x8 k8 = *(const u16x8*)(kh + (size_t)(ni * 16 + l15) * 256 + quad * 8);
            bf16x8 c, s;
#pragma unroll
            for (int j = 0; j < 8; ++j) {
                float v = b2f(k8[j]);
                c[j] = (short)f2b(__cosf(v));
                s[j] = (short)f2b(__sinf(v));
            }
            bfr[ni][0] = c; bfr[ni][1] = s;
        }
        f32x4 acc[4][4];
#pragma unroll
        for (int mi = 0; mi < 4; ++mi)
#pragma unroll
            for (int ni = 0; ni < 4; ++ni) acc[mi][ni] = f32x4{0.f, 0.f, 0.f, 0.f};
#pragma unroll
        for (int kc = 0; kc < 2; ++kc)
#pragma unroll
            for (int mi = 0; mi < 4; ++mi)
#pragma unroll
                for (int ni = 0; ni < 4; ++ni)
                    acc[mi][ni] = __builtin_amdgcn_mfma_f32_16x16x32_bf16(af[mi][kc], bfr[ni][kc], acc[mi][ni], 0, 0, 0);
#pragma unroll
        for (int mi = 0; mi < 4; ++mi)
#pragma unroll
            for (int ni = 0; ni < 4; ++ni)
#pragma unroll
                for (int r = 0; r < 4; ++r) {
                    float x = acc[mi][ni][r];
                    float sg = __builtin_amdgcn_rcpf(1.f + __expf(-x));
                    Sb[wave][mi * 16 + quad * 4 + r][ni * 16 + l15] = f2b(sg);
                }
        // PV: out[f][d] = sum_g S[f][g] V[g][d]   (all LDS here is wave-private; no barrier)
        f32x4 ao[4][2];
#pragma unroll
        for (int mi = 0; mi < 4; ++mi)
#pragma unroll
            for (int n2 = 0; n2 < 2; ++n2) ao[mi][n2] = f32x4{0.f, 0.f, 0.f, 0.f};
#pragma unroll
        for (int kc = 0; kc < 2; ++kc) {
            bf16x8 pb[2];
#pragma unroll
            for (int n2 = 0; n2 < 2; ++n2)
#pragma unroll
                for (int j = 0; j < 8; ++j)
                    pb[n2][j] = (short)Vb[wave][kc * 32 + quad * 8 + j][n2 * 16 + l15];
#pragma unroll
            for (int mi = 0; mi < 4; ++mi) {
                bf16x8 pa = *(const bf16x8*)&Sb[wave][mi * 16 + l15][kc * 32 + quad * 8];
#pragma unroll
                for (int n2 = 0; n2 < 2; ++n2)
                    ao[mi][n2] = __builtin_amdgcn_mfma_f32_16x16x32_bf16(pa, pb[n2], ao[mi][n2], 0, 0, 0);
            }
        }
#pragma unroll
        for (int mi = 0; mi < 4; ++mi)
#pragma unroll
            for (int n2 = 0; n2 < 2; ++n2)
#pragma unroll
                for (int r = 0; r < 4; ++r)
                    attf[base + (size_t)(mi * 16 + quad * 4 + r) * 256 + h * 32 + n2 * 16 + l15] =
                        ao[mi][n2][r];
    }
}

// ---- kernel 3: res = att(f32, in d_out) + theta @ W_lin^T, LayerNorm, write f32 out (same buf).
__global__ __launch_bounds__(512) void lin_ln_kernel(
    const float* __restrict__ theta, const float* __restrict__ Wl, const float* att,
    const float* __restrict__ gamma, const float* __restrict__ beta, float* out)
{
    int tid = threadIdx.x, wave = tid >> 6, lane = tid & 63;
    int l15 = lane & 15, quad = lane >> 4;
    int bm0 = blockIdx.x * 128;
    int wm0 = (wave >> 2) * 64, wn0 = (wave & 3) * 64;
    int wn = wave & 3;
    __shared__ u16 As[128][32];
    __shared__ u16 Bs[256][32];
    __shared__ float red1[128][4];
    __shared__ float red2[128][4];
    f32x4 acc[4][4];
#pragma unroll
    for (int mi = 0; mi < 4; ++mi)
#pragma unroll
        for (int ni = 0; ni < 4; ++ni) acc[mi][ni] = f32x4{0.f, 0.f, 0.f, 0.f};
    for (int k0 = 0; k0 < 256; k0 += 32) {
        {
            int r = tid >> 2; int c8 = (tid & 3) * 8;
            const float* p = theta + (size_t)(bm0 + r) * 256 + k0 + c8;
            f32x4 a = *(const f32x4*)p, b = *(const f32x4*)(p + 4);
            u16x8 v;
#pragma unroll
            for (int j = 0; j < 4; ++j) { v[j] = f2b(a[j]); v[j + 4] = f2b(b[j]); }
            *(u16x8*)&As[r][c8] = v;
        }
#pragma unroll
        for (int i = 0; i < 2; ++i) {
            int idx = tid * 2 + i; int r = idx >> 2; int c8 = (idx & 3) * 8;
            const float* p = Wl + (size_t)r * 256 + k0 + c8;
            f32x4 a = *(const f32x4*)p, b = *(const f32x4*)(p + 4);
            u16x8 v;
#pragma unroll
            for (int j = 0; j < 4; ++j) { v[j] = f2b(a[j]); v[j + 4] = f2b(b[j]); }
            *(u16x8*)&Bs[r][c8] = v;
        }
        __syncthreads();
        bf16x8 af[4], bfr[4];
#pragma unroll
        for (int mi = 0; mi < 4; ++mi) af[mi] = *(const bf16x8*)&As[wm0 + mi * 16 + l15][quad * 8];
#pragma unroll
        for (int ni = 0; ni < 4; ++ni) bfr[ni] = *(const bf16x8*)&Bs[wn0 + ni * 16 + l15][quad * 8];
#pragma unroll
        for (int mi = 0; mi < 4; ++mi)
#pragma unroll
            for (int ni = 0; ni < 4; ++ni)
                acc[mi][ni] = __builtin_amdgcn_mfma_f32_16x16x32_bf16(af[mi], bfr[ni], acc[mi][ni], 0, 0, 0);
        __syncthreads();
    }
    float gam[4], bet[4];
#pragma unroll
    for (int ni = 0; ni < 4; ++ni) {
        gam[ni] = gamma[wn0 + ni * 16 + l15];
        bet[ni] = beta[wn0 + ni * 16 + l15];
    }
    // add attention output (same elements this wave later writes; per-wave regions disjoint)
#pragma unroll
    for (int mi = 0; mi < 4; ++mi)
#pragma unroll
        for (int ni = 0; ni < 4; ++ni)
#pragma unroll
            for (int r = 0; r < 4; ++r)
                acc[mi][ni][r] += att[(size_t)(bm0 + wm0 + mi * 16 + quad * 4 + r) * 256 + wn0 + ni * 16 + l15];
    // row stats: per-quad 16-lane shfl reduce, cross-wave via LDS
#pragma unroll
    for (int mi = 0; mi < 4; ++mi)
#pragma unroll
        for (int r = 0; r < 4; ++r) {
            float s1 = 0.f, s2 = 0.f;
#pragma unroll
            for (int ni = 0; ni < 4; ++ni) { float x = acc[mi][ni][r]; s1 += x; s2 += x * x; }
#pragma unroll
            for (int off = 1; off < 16; off <<= 1) {
                s1 += __shfl_xor(s1, off);
                s2 += __shfl_xor(s2, off);
            }
            if (l15 == 0) {
                int lr = wm0 + mi * 16 + quad * 4 + r;
                red1[lr][wn] = s1; red2[lr][wn] = s2;
            }
        }
    __syncthreads();
#pragma unroll
    for (int mi = 0; mi < 4; ++mi)
#pragma unroll
        for (int r = 0; r < 4; ++r) {
            int lr = wm0 + mi * 16 + quad * 4 + r;
            float s1 = red1[lr][0] + red1[lr][1] + red1[lr][2] + red1[lr][3];
            float s2 = red2[lr][0] + red2[lr][1] + red2[lr][2] + red2[lr][3];
            float mu = s1 * (1.f / 256.f);
            float var = s2 * (1.f / 256.f) - mu * mu;
            float inv = rsqrtf(var + 1e-5f);
#pragma unroll
            for (int ni = 0; ni < 4; ++ni) {
                float y = (acc[mi][ni][r] - mu) * inv * gam[ni] + bet[ni];
                out[(size_t)(bm0 + lr) * 256 + wn0 + ni * 16 + l15] = y;
            }
        }
}

extern "C" void kernel_launch(void* const* d_in, const int* in_sizes, int n_in,
                              void* d_out, int out_size, void* d_ws, size_t ws_size,
                              hipStream_t stream)
{
    const float* theta = (const float*)d_in[0];
    const float* Q  = (const float*)d_in[1];
    const float* K  = (const float*)d_in[2];
    const float* V  = (const float*)d_in[3];
    const float* Wl = (const float*)d_in[4];
    const float* rotw = (const float*)d_in[5];
    const float* gam = (const float*)d_in[6];
    const float* bet = (const float*)d_in[7];
    int B = in_sizes[0] / (64 * 256);  // 1024
    u16* ws = (u16*)d_ws;
    size_t per = (size_t)B * 16384;
    u16* wsq = ws;
    u16* wsk = ws + per;
    u16* wsv = ws + 2 * per;
    u16* wT  = ws + 3 * per;   // 192 transposed bf16 256x256 mats (25.2MB); total ws 126MB
    float* outf = (float*)d_out;

    wtrans_kernel<<<dim3(4, 4, 192), 256, 0, stream>>>(Q, K, V, wT);
    qkv_gemm_kernel<<<dim3(B / 128, 2, 192), 256, 0, stream>>>(theta, wT, ws, B);
    attn_kernel<<<dim3(B), 256, 0, stream>>>(wsq, wsk, wsv, outf, rotw);
    lin_ln_kernel<<<dim3(B * 64 / 128), 512, 0, stream>>>(theta, Wl, outf, gam, bet, outf);
}

// Round 3
// 289.865 us; speedup vs baseline: 1.0770x; 1.0770x over previous
//
#include <hip/hip_runtime.h>

// Problem: B=1024, F=64, D_IN=D_OUT=256, H=8, dh=32. f32 in/out, bf16 MFMA compute.
typedef __attribute__((ext_vector_type(8))) short bf16x8;
typedef __attribute__((ext_vector_type(8))) unsigned short u16x8;
typedef __attribute__((ext_vector_type(4))) unsigned short u16x4;
typedef __attribute__((ext_vector_type(4))) float f32x4;
typedef unsigned short u16;

__device__ __forceinline__ float b2f(u16 u) {
    return __builtin_bit_cast(float, (unsigned)u << 16);
}
__device__ __forceinline__ u16 f2b(float f) {  // RNE f32->bf16
    unsigned i = __builtin_bit_cast(unsigned, f);
    return (u16)((i + 0x7FFFu + ((i >> 16) & 1u)) >> 16);
}
__device__ __forceinline__ void async_cp16(const u16* g, u16* l) {
    __builtin_amdgcn_global_load_lds((const __attribute__((address_space(1))) void*)g,
                                     (__attribute__((address_space(3))) void*)l, 16, 0, 0);
}

// ---- kernel 0: convert f32 weights [d][w] -> bf16 WT [w][d] (K-contig for MFMA B-op)
__global__ __launch_bounds__(256) void wtrans_kernel(
    const float* __restrict__ Q, const float* __restrict__ K, const float* __restrict__ V,
    u16* __restrict__ WT)
{
    int z = blockIdx.z; int m = z >> 6, f = z & 63;
    const float* src = (m == 0 ? Q : (m == 1 ? K : V)) + (size_t)f * 65536;
    u16* dst = WT + (size_t)z * 65536;
    int w0 = blockIdx.x * 64, d0 = blockIdx.y * 64;
    __shared__ u16 tile[64][68];
    int tid = threadIdx.x;
#pragma unroll
    for (int i = 0; i < 2; ++i) {
        int idx = tid * 2 + i; int r = idx >> 3; int c8 = (idx & 7) * 8;
        const float* p = src + (size_t)(d0 + r) * 256 + w0 + c8;
        f32x4 a = *(const f32x4*)p, b = *(const f32x4*)(p + 4);
        u16x4 lo, hi;
#pragma unroll
        for (int j = 0; j < 4; ++j) { lo[j] = f2b(a[j]); hi[j] = f2b(b[j]); }
        *(u16x4*)&tile[r][c8] = lo;
        *(u16x4*)&tile[r][c8 + 4] = hi;
    }
    __syncthreads();
#pragma unroll
    for (int i = 0; i < 2; ++i) {
        int idx = tid * 2 + i; int rw = idx >> 3; int c8 = (idx & 7) * 8;
        u16x8 v;
#pragma unroll
        for (int j = 0; j < 8; ++j) v[j] = tile[c8 + j][rw];
        *(u16x8*)(dst + (size_t)(w0 + rw) * 256 + d0 + c8) = v;
    }
}

// ---- kernel 1: q,k,v for one f in ONE block (m fused). A staged once (f32->bf16,
// XOR-swizzled LDS) then held in registers; B double-buffered via global_load_lds.
__global__ __launch_bounds__(256, 2) void qkv_gemm_kernel(
    const float* __restrict__ theta, const u16* __restrict__ WT, u16* __restrict__ ws, int B)
{
    int f = blockIdx.z;
    int bm0 = blockIdx.x * 128, bn0 = blockIdx.y * 128;
    // 64KB union: phase1 = A tile 128 rows x 512B (chunk-swizzled); phase2 = B dbuf 2x8KB.
    __shared__ u16 smem[32768];
    int tid = threadIdx.x, wave = tid >> 6, lane = tid & 63;
    int l15 = lane & 15, quad = lane >> 4;
    int wm0 = (wave >> 1) * 64, wn0 = (wave & 1) * 64;

    // phase 1: stage A (128x256) f32->bf16. chunk c of row r stored at pos c^(r&7).
    const float* Af = theta + (size_t)f * 256;
#pragma unroll
    for (int p = 0; p < 16; ++p) {
        int id = p * 256 + tid;          // 4096 16B-chunks
        int r = id >> 5, c = id & 31;
        const float* g = Af + (size_t)(bm0 + r) * 16384 + c * 8;
        f32x4 a = *(const f32x4*)g, b = *(const f32x4*)(g + 4);
        u16x8 v;
#pragma unroll
        for (int j = 0; j < 4; ++j) { v[j] = f2b(a[j]); v[j + 4] = f2b(b[j]); }
        *(u16x8*)&smem[r * 256 + ((c ^ (r & 7)) * 8)] = v;
    }
    __syncthreads();
    // extract A fragments for all K into registers: af[mi][kk]
    bf16x8 af[4][8];
#pragma unroll
    for (int mi = 0; mi < 4; ++mi)
#pragma unroll
        for (int kk = 0; kk < 8; ++kk) {
            int row = wm0 + mi * 16 + l15;
            int pos = (kk * 4 + quad) ^ (l15 & 7);
            af[mi][kk] = *(const bf16x8*)&smem[row * 256 + pos * 8];
        }
    __syncthreads();  // everyone done reading A before B overwrites smem[0:8KB]

    // phase 2: 24 iterations (m=0..2 x kk=0..7), B tile 128x32 double-buffered
    auto issueB = [&](int it) {
        int m = it >> 3, kk = it & 7, buf = it & 1;
        const u16* Bt = WT + (size_t)(m * 64 + f) * 65536;
#pragma unroll
        for (int i = 0; i < 2; ++i) {
            int r0 = wave * 32 + i * 16;
            const u16* g = Bt + (size_t)(bn0 + r0 + (lane >> 2)) * 256 + kk * 32 + (lane & 3) * 8;
            async_cp16(g, &smem[buf * 4096 + r0 * 32]);
        }
    };
    issueB(0);
    f32x4 acc[4][4];
#pragma unroll
    for (int it = 0; it < 24; ++it) {
        int kk = it & 7, buf = it & 1;
        if (kk == 0) {
#pragma unroll
            for (int mi = 0; mi < 4; ++mi)
#pragma unroll
                for (int ni = 0; ni < 4; ++ni) acc[mi][ni] = f32x4{0.f, 0.f, 0.f, 0.f};
        }
        __syncthreads();             // B[it] landed; previous compute done
        if (it < 23) issueB(it + 1);
        bf16x8 bfr[4];
#pragma unroll
        for (int ni = 0; ni < 4; ++ni)
            bfr[ni] = *(const bf16x8*)&smem[buf * 4096 + (wn0 + ni * 16 + l15) * 32 + quad * 8];
#pragma unroll
        for (int mi = 0; mi < 4; ++mi)
#pragma unroll
            for (int ni = 0; ni < 4; ++ni)
                acc[mi][ni] = __builtin_amdgcn_mfma_f32_16x16x32_bf16(af[mi][kk], bfr[ni], acc[mi][ni], 0, 0, 0);
        if (kk == 7) {
            int m = it >> 3;
            u16* C = ws + (size_t)m * B * 16384 + (size_t)f * 256;
#pragma unroll
            for (int mi = 0; mi < 4; ++mi)
#pragma unroll
                for (int ni = 0; ni < 4; ++ni)
#pragma unroll
                    for (int r = 0; r < 4; ++r)
                        C[(size_t)(bm0 + wm0 + mi * 16 + quad * 4 + r) * 16384 + bn0 + wn0 + ni * 16 + l15] =
                            f2b(acc[mi][ni][r]);
        }
    }
}

// ---- kernel 2: attention. 1 block per b, 1 wave per head (x2 sequential heads).
__global__ __launch_bounds__(256) void attn_kernel(
    const u16* __restrict__ qws, const u16* __restrict__ kws, const u16* __restrict__ vws,
    float* __restrict__ attf, const float* __restrict__ rotw)
{
    int b = blockIdx.x;
    int tid = threadIdx.x, wave = tid >> 6, lane = tid & 63;
    int l15 = lane & 15, quad = lane >> 4;
    __shared__ u16 Sb[4][64][72];
    __shared__ u16 Vb[4][64][32];
    const size_t base = (size_t)b * (64 * 256);
    float rw[8];
    {
        f32x4 r0 = *(const f32x4*)(rotw + quad * 8);
        f32x4 r1 = *(const f32x4*)(rotw + quad * 8 + 4);
#pragma unroll
        for (int j = 0; j < 4; ++j) { rw[j] = r0[j]; rw[j + 4] = r1[j]; }
    }
    for (int hi = 0; hi < 2; ++hi) {
        int h = wave + hi * 4;
        const u16* qh = qws + base + h * 32;
        const u16* kh = kws + base + h * 32;
        const u16* vh = vws + base + h * 32;
#pragma unroll
        for (int i = 0; i < 4; ++i) {
            int row = i * 16 + (lane >> 2); int c8 = (lane & 3) * 8;
            *(u16x8*)&Vb[wave][row][c8] = *(const u16x8*)(vh + (size_t)row * 256 + c8);
        }
        bf16x8 af[4][2], bfr[4][2];
#pragma unroll
        for (int mi = 0; mi < 4; ++mi) {
            u16x8 q8 = *(const u16x8*)(qh + (size_t)(mi * 16 + l15) * 256 + quad * 8);
            bf16x8 c, s;
#pragma unroll
            for (int j = 0; j < 8; ++j) {
                float v = b2f(q8[j]);
                c[j] = (short)f2b(__cosf(v) * rw[j]);
                s[j] = (short)f2b(__sinf(v) * rw[j]);
            }
            af[mi][0] = c; af[mi][1] = s;
        }
#pragma unroll
        for (int ni = 0; ni < 4; ++ni) {
            u16x8 k8 = *(const u16x8*)(kh + (size_t)(ni * 16 + l15) * 256 + quad * 8);
            bf16x8 c, s;
#pragma unroll
            for (int j = 0; j < 8; ++j) {
                float v = b2f(k8[j]);
                c[j] = (short)f2b(__cosf(v));
                s[j] = (short)f2b(__sinf(v));
            }
            bfr[ni][0] = c; bfr[ni][1] = s;
        }
        f32x4 acc[4][4];
#pragma unroll
        for (int mi = 0; mi < 4; ++mi)
#pragma unroll
            for (int ni = 0; ni < 4; ++ni) acc[mi][ni] = f32x4{0.f, 0.f, 0.f, 0.f};
#pragma unroll
        for (int kc = 0; kc < 2; ++kc)
#pragma unroll
            for (int mi = 0; mi < 4; ++mi)
#pragma unroll
                for (int ni = 0; ni < 4; ++ni)
                    acc[mi][ni] = __builtin_amdgcn_mfma_f32_16x16x32_bf16(af[mi][kc], bfr[ni][kc], acc[mi][ni], 0, 0, 0);
#pragma unroll
        for (int mi = 0; mi < 4; ++mi)
#pragma unroll
            for (int ni = 0; ni < 4; ++ni)
#pragma unroll
                for (int r = 0; r < 4; ++r) {
                    float x = acc[mi][ni][r];
                    float sg = __builtin_amdgcn_rcpf(1.f + __expf(-x));
                    Sb[wave][mi * 16 + quad * 4 + r][ni * 16 + l15] = f2b(sg);
                }
        f32x4 ao[4][2];
#pragma unroll
        for (int mi = 0; mi < 4; ++mi)
#pragma unroll
            for (int n2 = 0; n2 < 2; ++n2) ao[mi][n2] = f32x4{0.f, 0.f, 0.f, 0.f};
#pragma unroll
        for (int kc = 0; kc < 2; ++kc) {
            bf16x8 pb[2];
#pragma unroll
            for (int n2 = 0; n2 < 2; ++n2)
#pragma unroll
                for (int j = 0; j < 8; ++j)
                    pb[n2][j] = (short)Vb[wave][kc * 32 + quad * 8 + j][n2 * 16 + l15];
#pragma unroll
            for (int mi = 0; mi < 4; ++mi) {
                bf16x8 pa = *(const bf16x8*)&Sb[wave][mi * 16 + l15][kc * 32 + quad * 8];
#pragma unroll
                for (int n2 = 0; n2 < 2; ++n2)
                    ao[mi][n2] = __builtin_amdgcn_mfma_f32_16x16x32_bf16(pa, pb[n2], ao[mi][n2], 0, 0, 0);
            }
        }
#pragma unroll
        for (int mi = 0; mi < 4; ++mi)
#pragma unroll
            for (int n2 = 0; n2 < 2; ++n2)
#pragma unroll
                for (int r = 0; r < 4; ++r)
                    attf[base + (size_t)(mi * 16 + quad * 4 + r) * 256 + h * 32 + n2 * 16 + l15] =
                        ao[mi][n2][r];
    }
}

// ---- kernel 3: res = att(f32, in d_out) + theta @ W_lin^T, LayerNorm, f32 out (same buf).
__global__ __launch_bounds__(512) void lin_ln_kernel(
    const float* __restrict__ theta, const float* __restrict__ Wl, const float* att,
    const float* __restrict__ gamma, const float* __restrict__ beta, float* out)
{
    int tid = threadIdx.x, wave = tid >> 6, lane = tid & 63;
    int l15 = lane & 15, quad = lane >> 4;
    int bm0 = blockIdx.x * 128;
    int wm0 = (wave >> 2) * 64, wn0 = (wave & 3) * 64;
    int wn = wave & 3;
    __shared__ u16 As[128][32];
    __shared__ u16 Bs[256][32];
    __shared__ float red1[128][4];
    __shared__ float red2[128][4];
    f32x4 acc[4][4];
#pragma unroll
    for (int mi = 0; mi < 4; ++mi)
#pragma unroll
        for (int ni = 0; ni < 4; ++ni) acc[mi][ni] = f32x4{0.f, 0.f, 0.f, 0.f};
    for (int k0 = 0; k0 < 256; k0 += 32) {
        {
            int r = tid >> 2; int c8 = (tid & 3) * 8;
            const float* p = theta + (size_t)(bm0 + r) * 256 + k0 + c8;
            f32x4 a = *(const f32x4*)p, b = *(const f32x4*)(p + 4);
            u16x8 v;
#pragma unroll
            for (int j = 0; j < 4; ++j) { v[j] = f2b(a[j]); v[j + 4] = f2b(b[j]); }
            *(u16x8*)&As[r][c8] = v;
        }
#pragma unroll
        for (int i = 0; i < 2; ++i) {
            int idx = tid * 2 + i; int r = idx >> 2; int c8 = (idx & 3) * 8;
            const float* p = Wl + (size_t)r * 256 + k0 + c8;
            f32x4 a = *(const f32x4*)p, b = *(const f32x4*)(p + 4);
            u16x8 v;
#pragma unroll
            for (int j = 0; j < 4; ++j) { v[j] = f2b(a[j]); v[j + 4] = f2b(b[j]); }
            *(u16x8*)&Bs[r][c8] = v;
        }
        __syncthreads();
        bf16x8 af[4], bfr[4];
#pragma unroll
        for (int mi = 0; mi < 4; ++mi) af[mi] = *(const bf16x8*)&As[wm0 + mi * 16 + l15][quad * 8];
#pragma unroll
        for (int ni = 0; ni < 4; ++ni) bfr[ni] = *(const bf16x8*)&Bs[wn0 + ni * 16 + l15][quad * 8];
#pragma unroll
        for (int mi = 0; mi < 4; ++mi)
#pragma unroll
            for (int ni = 0; ni < 4; ++ni)
                acc[mi][ni] = __builtin_amdgcn_mfma_f32_16x16x32_bf16(af[mi], bfr[ni], acc[mi][ni], 0, 0, 0);
        __syncthreads();
    }
    float gam[4], bet[4];
#pragma unroll
    for (int ni = 0; ni < 4; ++ni) {
        gam[ni] = gamma[wn0 + ni * 16 + l15];
        bet[ni] = beta[wn0 + ni * 16 + l15];
    }
#pragma unroll
    for (int mi = 0; mi < 4; ++mi)
#pragma unroll
        for (int ni = 0; ni < 4; ++ni)
#pragma unroll
            for (int r = 0; r < 4; ++r)
                acc[mi][ni][r] += att[(size_t)(bm0 + wm0 + mi * 16 + quad * 4 + r) * 256 + wn0 + ni * 16 + l15];
#pragma unroll
    for (int mi = 0; mi < 4; ++mi)
#pragma unroll
        for (int r = 0; r < 4; ++r) {
            float s1 = 0.f, s2 = 0.f;
#pragma unroll
            for (int ni = 0; ni < 4; ++ni) { float x = acc[mi][ni][r]; s1 += x; s2 += x * x; }
#pragma unroll
            for (int off = 1; off < 16; off <<= 1) {
                s1 += __shfl_xor(s1, off);
                s2 += __shfl_xor(s2, off);
            }
            if (l15 == 0) {
                int lr = wm0 + mi * 16 + quad * 4 + r;
                red1[lr][wn] = s1; red2[lr][wn] = s2;
            }
        }
    __syncthreads();
#pragma unroll
    for (int mi = 0; mi < 4; ++mi)
#pragma unroll
        for (int r = 0; r < 4; ++r) {
            int lr = wm0 + mi * 16 + quad * 4 + r;
            float s1 = red1[lr][0] + red1[lr][1] + red1[lr][2] + red1[lr][3];
            float s2 = red2[lr][0] + red2[lr][1] + red2[lr][2] + red2[lr][3];
            float mu = s1 * (1.f / 256.f);
            float var = s2 * (1.f / 256.f) - mu * mu;
            float inv = rsqrtf(var + 1e-5f);
#pragma unroll
            for (int ni = 0; ni < 4; ++ni) {
                float y = (acc[mi][ni][r] - mu) * inv * gam[ni] + bet[ni];
                out[(size_t)(bm0 + lr) * 256 + wn0 + ni * 16 + l15] = y;
            }
        }
}

extern "C" void kernel_launch(void* const* d_in, const int* in_sizes, int n_in,
                              void* d_out, int out_size, void* d_ws, size_t ws_size,
                              hipStream_t stream)
{
    const float* theta = (const float*)d_in[0];
    const float* Q  = (const float*)d_in[1];
    const float* K  = (const float*)d_in[2];
    const float* V  = (const float*)d_in[3];
    const float* Wl = (const float*)d_in[4];
    const float* rotw = (const float*)d_in[5];
    const float* gam = (const float*)d_in[6];
    const float* bet = (const float*)d_in[7];
    int B = in_sizes[0] / (64 * 256);  // 1024
    u16* ws = (u16*)d_ws;
    size_t per = (size_t)B * 16384;
    u16* wsq = ws;
    u16* wsk = ws + per;
    u16* wsv = ws + 2 * per;
    u16* wT  = ws + 3 * per;   // 192 transposed bf16 256x256 mats; total ws ~126MB
    float* outf = (float*)d_out;

    wtrans_kernel<<<dim3(4, 4, 192), 256, 0, stream>>>(Q, K, V, wT);
    qkv_gemm_kernel<<<dim3(B / 128, 2, 64), 256, 0, stream>>>(theta, wT, ws, B);
    attn_kernel<<<dim3(B), 256, 0, stream>>>(wsq, wsk, wsv, outf, rotw);
    lin_ln_kernel<<<dim3(B * 64 / 128), 512, 0, stream>>>(theta, Wl, outf, gam, bet, outf);
}